// Round 3
// baseline (3562.420 us; speedup 1.0000x reference)
//
#include <hip/hip_runtime.h>

#define BATCH 256
#define TSTEPS 2048
#define INSZ 64
#define HID 128
#define OUTSZ 64
#define CHUNK 32                 // timesteps of x per staging buffer
#define NCHUNK (TSTEPS / CHUNK)  // 64

typedef float v2f __attribute__((ext_vector_type(2)));
typedef float v4f __attribute__((ext_vector_type(4)));

// ONE WAVE per batch element: no __syncthreads anywhere (same-wave LDS ops are
// in-order), so no vmcnt(0) barrier drains. Lane l owns rows (l, l+64).
// All weights in VGPRs (~384). h broadcast via LDS; x via global_load_lds
// double-buffered 32-step chunks with a manual vmcnt wait once per chunk.
__launch_bounds__(64, 1)
__global__ void rnn_wave_kernel(const float* __restrict__ x,
                                const float* __restrict__ Wx_w,
                                const float* __restrict__ Wx_b,
                                const float* __restrict__ Wh_w,
                                const float* __restrict__ Wh_b,
                                const float* __restrict__ fc_w,
                                const float* __restrict__ fc_b,
                                float* __restrict__ out) {
  const int b = blockIdx.x;
  const int l = threadIdx.x;  // 0..63
  const int r0 = l;
  const int r1 = l + 64;

  __shared__ __align__(16) float hsm[HID];
  __shared__ __align__(16) float xsm[2][CHUNK * INSZ];  // 2 x 8KB

  // ---- weights into registers (k-contiguous float2 pairs for v_pk_fma_f32) ----
  v2f wh0[64], wh1[64], wx0[32], wx1[32];
  {
    const v2f* p0 = (const v2f*)(Wh_w + r0 * HID);
    const v2f* p1 = (const v2f*)(Wh_w + r1 * HID);
#pragma unroll
    for (int i = 0; i < 64; ++i) { wh0[i] = p0[i]; wh1[i] = p1[i]; }
    const v2f* q0 = (const v2f*)(Wx_w + r0 * INSZ);
    const v2f* q1 = (const v2f*)(Wx_w + r1 * INSZ);
#pragma unroll
    for (int i = 0; i < 32; ++i) { wx0[i] = q0[i]; wx1[i] = q1[i]; }
  }
  const float bc0 = Wx_b[r0] + Wh_b[r0];
  const float bc1 = Wx_b[r1] + Wh_b[r1];

  const float* xg = x + (size_t)b * TSTEPS * INSZ;

  // ---- init h = 0 ----
  hsm[r0] = 0.f;
  hsm[r1] = 0.f;

  // ---- stage chunk 0 into buffer 0 (8 x 1KB global_load_lds, width 16) ----
#pragma unroll
  for (int i = 0; i < 8; ++i) {
    const __attribute__((address_space(1))) float* g =
        (const __attribute__((address_space(1))) float*)(xg + i * 256 + l * 4);
    __attribute__((address_space(3))) float* d =
        (__attribute__((address_space(3))) float*)(&xsm[0][i * 256]);
    __builtin_amdgcn_global_load_lds(g, d, 16, 0, 0);
  }

  // ---- recurrence ----
  for (int t = 0; t < TSTEPS; ++t) {
    const int buf = (t >> 5) & 1;

    if ((t & (CHUNK - 1)) == 0) {
      // loads for the chunk we are ABOUT to consume were issued 32 steps ago
      asm volatile("s_waitcnt vmcnt(0)" ::: "memory");
      const int nc = (t >> 5) + 1;
      if (nc < NCHUNK) {
        const float* src = xg + (size_t)nc * CHUNK * INSZ;
#pragma unroll
        for (int i = 0; i < 8; ++i) {
          const __attribute__((address_space(1))) float* g =
              (const __attribute__((address_space(1))) float*)(src + i * 256 + l * 4);
          __attribute__((address_space(3))) float* d =
              (__attribute__((address_space(3))) float*)(&xsm[buf ^ 1][i * 256]);
          __builtin_amdgcn_global_load_lds(g, d, 16, 0, 0);
        }
      }
    }

    // ---- x-part: 64 pk_fma (rows r0,r1), broadcast reads from LDS chunk ----
    const float* xs = &xsm[buf][(t & (CHUNK - 1)) * INSZ];
    v2f ax0 = {0.f, 0.f}, ax1 = {0.f, 0.f};
#pragma unroll
    for (int i = 0; i < 16; ++i) {
      v4f xv = *(const v4f*)&xs[i * 4];
      v2f lo = __builtin_shufflevector(xv, xv, 0, 1);
      v2f hi = __builtin_shufflevector(xv, xv, 2, 3);
      ax0 = __builtin_elementwise_fma(wx0[2 * i], lo, ax0);
      ax0 = __builtin_elementwise_fma(wx0[2 * i + 1], hi, ax0);
      ax1 = __builtin_elementwise_fma(wx1[2 * i], lo, ax1);
      ax1 = __builtin_elementwise_fma(wx1[2 * i + 1], hi, ax1);
    }

    // ---- h-part: 128 pk_fma, 32 broadcast b128 reads ----
    v2f h0a = {0.f, 0.f}, h0b = {0.f, 0.f};
    v2f h1a = {0.f, 0.f}, h1b = {0.f, 0.f};
#pragma unroll
    for (int i = 0; i < 32; ++i) {
      v4f hv = *(const v4f*)&hsm[i * 4];
      v2f lo = __builtin_shufflevector(hv, hv, 0, 1);
      v2f hi = __builtin_shufflevector(hv, hv, 2, 3);
      h0a = __builtin_elementwise_fma(wh0[2 * i], lo, h0a);
      h0b = __builtin_elementwise_fma(wh0[2 * i + 1], hi, h0b);
      h1a = __builtin_elementwise_fma(wh1[2 * i], lo, h1a);
      h1b = __builtin_elementwise_fma(wh1[2 * i + 1], hi, h1b);
    }

    float z0 = bc0 + (ax0.x + ax0.y) + ((h0a.x + h0b.x) + (h0a.y + h0b.y));
    float z1 = bc1 + (ax1.x + ax1.y) + ((h1a.x + h1b.x) + (h1a.y + h1b.y));

    // tanh(z) = 1 - 2/(exp2(2*z*log2e)+1)
    float e0 = __builtin_amdgcn_exp2f(z0 * 2.8853900817779268f);
    float e1 = __builtin_amdgcn_exp2f(z1 * 2.8853900817779268f);
    float hn0 = 1.f - 2.f * __builtin_amdgcn_rcpf(e0 + 1.f);
    float hn1 = 1.f - 2.f * __builtin_amdgcn_rcpf(e1 + 1.f);

    hsm[r0] = hn0;  // same-wave DS ops are in-order: next step's reads see these
    hsm[r1] = hn1;
  }

  // ---- epilogue: logits + softmax over 64 outputs, one per lane ----
  {
    float a = fc_b[l];
    const float* fr = fc_w + l * HID;
#pragma unroll
    for (int k = 0; k < HID; k += 4) {
      v4f w4 = *(const v4f*)&fr[k];
      v4f hv = *(const v4f*)&hsm[k];  // broadcast
      a = fmaf(w4.x, hv.x, a);
      a = fmaf(w4.y, hv.y, a);
      a = fmaf(w4.z, hv.z, a);
      a = fmaf(w4.w, hv.w, a);
    }
    float m = a;
#pragma unroll
    for (int off = 32; off >= 1; off >>= 1) m = fmaxf(m, __shfl_xor(m, off, 64));
    float e = __builtin_amdgcn_exp2f((a - m) * 1.4426950408889634f);
    float ssum = e;
#pragma unroll
    for (int off = 32; off >= 1; off >>= 1) ssum += __shfl_xor(ssum, off, 64);
    out[b * OUTSZ + l] = e / ssum;
  }
}

extern "C" void kernel_launch(void* const* d_in, const int* in_sizes, int n_in,
                              void* d_out, int out_size, void* d_ws, size_t ws_size,
                              hipStream_t stream) {
  const float* x    = (const float*)d_in[0];
  const float* Wx_w = (const float*)d_in[1];
  const float* Wx_b = (const float*)d_in[2];
  const float* Wh_w = (const float*)d_in[3];
  const float* Wh_b = (const float*)d_in[4];
  const float* fc_w = (const float*)d_in[5];
  const float* fc_b = (const float*)d_in[6];
  float* out = (float*)d_out;

  rnn_wave_kernel<<<BATCH, 64, 0, stream>>>(x, Wx_w, Wx_b, Wh_w, Wh_b, fc_w, fc_b, out);
}

// Round 4
// 813.557 us; speedup vs baseline: 4.3788x; 4.3788x over previous
//
#include <hip/hip_runtime.h>

#define BATCH 256
#define TSTEPS 2048
#define INSZ 64
#define HID 128
#define OUTSZ 64
#define HPAD 68                  // s=1 half at float-offset 68: disjoint banks vs s=0
#define CHUNK 16                 // timesteps of x per staging buffer (4KB)
#define NCHUNK (TSTEPS / CHUNK)  // 128

typedef float v2f __attribute__((ext_vector_type(2)));
typedef float v4f __attribute__((ext_vector_type(4)));

#define AS1 __attribute__((address_space(1)))
#define AS3 __attribute__((address_space(3)))

// 256 threads = 4 waves per batch element. tid=(j<<1)|s: j=output row, s=k-half.
// Weights in VGPRs (~96 floats/thread -> no spill). h double-buffered in LDS with
// bank-disjoint padding. x staged global->LDS in 16-step chunks (1 vmem
// instr/thread/chunk). Barriers are raw s_barrier + lgkmcnt(0) ONLY -- vmcnt is
// drained once per chunk, folded into the barrier 15 steps after issue (free).
__launch_bounds__(256, 1)
__global__ void rnn_block_kernel(const float* __restrict__ x,
                                 const float* __restrict__ Wx_w,
                                 const float* __restrict__ Wx_b,
                                 const float* __restrict__ Wh_w,
                                 const float* __restrict__ Wh_b,
                                 const float* __restrict__ fc_w,
                                 const float* __restrict__ fc_b,
                                 float* __restrict__ out) {
  const int b = blockIdx.x;
  const int tid = threadIdx.x;
  const int s = tid & 1;   // k-half: 0 -> k in [0,64), 1 -> k in [64,128)
  const int j = tid >> 1;  // output row 0..127
  const int jp = j + ((j >> 6) << 2);  // padded h index

  __shared__ __align__(16) float hbuf[2][2 * HPAD];
  __shared__ __align__(16) float xsm[2][CHUNK * INSZ];  // 2 x 4KB

  // ---- weights into registers ----
  v2f wh[32], wx[16];
  {
    const v2f* p = (const v2f*)(Wh_w + j * HID + s * 64);
#pragma unroll
    for (int i = 0; i < 32; ++i) wh[i] = p[i];
    const v2f* q = (const v2f*)(Wx_w + j * INSZ + s * 32);
#pragma unroll
    for (int i = 0; i < 16; ++i) wx[i] = q[i];
  }
  const float bc = Wx_b[j] + Wh_b[j];

  const float* xg = x + (size_t)b * TSTEPS * INSZ;

  // ---- init h0 = 0 ----
  if (tid < 2 * HPAD) hbuf[0][tid] = 0.f;

  // ---- stage chunk 0 (each thread: one 16B gload_lds; wave-uniform LDS base) ----
  {
    const AS1 float* g = (const AS1 float*)(xg + tid * 4);
    AS3 float* d = (AS3 float*)(&xsm[0][(tid >> 6) * 256]);
    __builtin_amdgcn_global_load_lds(g, d, 16, 0, 0);
  }
  // chunk 0 + h-init visible to all waves before first step
  asm volatile("s_waitcnt vmcnt(0) lgkmcnt(0)\ns_barrier" ::: "memory");

  // ---- recurrence ----
  for (int tc = 0; tc < NCHUNK; ++tc) {
    // issue next chunk's loads (target buffer's readers finished last step's barrier)
    if (tc + 1 < NCHUNK) {
      const AS1 float* g =
          (const AS1 float*)(xg + (size_t)(tc + 1) * CHUNK * INSZ + tid * 4);
      AS3 float* d = (AS3 float*)(&xsm[(tc + 1) & 1][(tid >> 6) * 256]);
      __builtin_amdgcn_global_load_lds(g, d, 16, 0, 0);
    }
    const float* xc = xsm[tc & 1];

#pragma unroll
    for (int ts = 0; ts < CHUNK; ++ts) {
      // parity: global step = tc*16+ts, CHUNK even -> parity = ts&1 (static)
      const float* hin = hbuf[ts & 1];
      float* hout = hbuf[(ts & 1) ^ 1];

      // issue x reads first (arrive earliest), then h reads
      const float* xs = xc + ts * INSZ + s * 32;
      v4f xv[8];
#pragma unroll
      for (int i = 0; i < 8; ++i) xv[i] = *(const v4f*)&xs[i * 4];

      const float* hs = hin + s * HPAD;
      v4f hv[16];
#pragma unroll
      for (int i = 0; i < 16; ++i) hv[i] = *(const v4f*)&hs[i * 4];

      // x-part: 16 pk_fma
      v2f a0 = {0.f, 0.f}, a1 = {0.f, 0.f};
#pragma unroll
      for (int i = 0; i < 8; ++i) {
        v2f lo = __builtin_shufflevector(xv[i], xv[i], 0, 1);
        v2f hi = __builtin_shufflevector(xv[i], xv[i], 2, 3);
        a0 = __builtin_elementwise_fma(wx[2 * i], lo, a0);
        a1 = __builtin_elementwise_fma(wx[2 * i + 1], hi, a1);
      }
      // h-part: 32 pk_fma
      v2f b0 = {0.f, 0.f}, b1 = {0.f, 0.f};
#pragma unroll
      for (int i = 0; i < 16; ++i) {
        v2f lo = __builtin_shufflevector(hv[i], hv[i], 0, 1);
        v2f hi = __builtin_shufflevector(hv[i], hv[i], 2, 3);
        b0 = __builtin_elementwise_fma(wh[2 * i], lo, b0);
        b1 = __builtin_elementwise_fma(wh[2 * i + 1], hi, b1);
      }

      float acc = ((a0.x + a0.y) + (a1.x + a1.y)) +
                  ((b0.x + b0.y) + (b1.x + b1.y));
      acc += __shfl_xor(acc, 1, 64);  // combine the two k-halves

      // tanh(z) = 1 - 2/(exp2(2*z*log2e)+1)
      float z = acc + bc;
      float e = __builtin_amdgcn_exp2f(z * 2.8853900817779268f);
      float hn = 1.f - 2.f * __builtin_amdgcn_rcpf(e + 1.f);

      if (s == 0) hout[jp] = hn;

      if (ts == CHUNK - 1) {
        // fold the chunk-boundary vmcnt drain into this barrier: the loads it
        // waits on were issued 15 steps ago -> wait is free. Per-wave vmcnt(0)
        // before s_barrier => all waves' gload_lds landed once barrier clears.
        asm volatile("s_waitcnt vmcnt(0) lgkmcnt(0)\ns_barrier" ::: "memory");
      } else {
        asm volatile("s_waitcnt lgkmcnt(0)\ns_barrier" ::: "memory");
      }
    }
  }

  // ---- epilogue: logits = h_T @ fc_w^T + fc_b, softmax over 64, one wave ----
  // TSTEPS even -> final h in hbuf[0] (padded layout)
  if (tid < 64) {
    float a = fc_b[tid];
    const float* fr = fc_w + tid * HID;
#pragma unroll
    for (int k = 0; k < HID; k += 4) {
      v4f w4 = *(const v4f*)&fr[k];
      const float* hf = &hbuf[0][k + ((k >> 6) << 2)];
      a = fmaf(w4.x, hf[0], a);
      a = fmaf(w4.y, hf[1], a);
      a = fmaf(w4.z, hf[2], a);
      a = fmaf(w4.w, hf[3], a);
    }
    float m = a;
#pragma unroll
    for (int off = 32; off >= 1; off >>= 1) m = fmaxf(m, __shfl_xor(m, off, 64));
    float e = __builtin_amdgcn_exp2f((a - m) * 1.4426950408889634f);
    float ssum = e;
#pragma unroll
    for (int off = 32; off >= 1; off >>= 1) ssum += __shfl_xor(ssum, off, 64);
    out[b * OUTSZ + tid] = e / ssum;
  }
}

extern "C" void kernel_launch(void* const* d_in, const int* in_sizes, int n_in,
                              void* d_out, int out_size, void* d_ws, size_t ws_size,
                              hipStream_t stream) {
  const float* x    = (const float*)d_in[0];
  const float* Wx_w = (const float*)d_in[1];
  const float* Wx_b = (const float*)d_in[2];
  const float* Wh_w = (const float*)d_in[3];
  const float* Wh_b = (const float*)d_in[4];
  const float* fc_w = (const float*)d_in[5];
  const float* fc_b = (const float*)d_in[6];
  float* out = (float*)d_out;

  rnn_block_kernel<<<BATCH, 256, 0, stream>>>(x, Wx_w, Wx_b, Wh_w, Wh_b, fc_w, fc_b, out);
}

// Round 5
// 551.467 us; speedup vs baseline: 6.4599x; 1.4753x over previous
//
#include <hip/hip_runtime.h>

#define BATCH 256
#define TSTEPS 2048
#define INSZ 64
#define HID 128
#define OUTSZ 64
#define CHUNK 16                 // timesteps of x per staging buffer (4KB)
#define NCHUNK (TSTEPS / CHUNK)  // 128

typedef float v2f __attribute__((ext_vector_type(2)));
typedef float v4f __attribute__((ext_vector_type(4)));

#define AS1 __attribute__((address_space(1)))
#define AS3 __attribute__((address_space(3)))

// DPP cross-lane move (VALU pipe, no LDS). All lanes valid for our patterns.
template <int CTRL>
__device__ __forceinline__ float dppf(float v) {
  return __int_as_float(__builtin_amdgcn_update_dpp(
      0, __float_as_int(v), CTRL, 0xF, 0xF, true));
}
#define DPP_XOR1 0xB1    // quad_perm:[1,0,3,2]
#define DPP_XOR2 0x4E    // quad_perm:[2,3,0,1]
#define DPP_XOR15 0x140  // row_mirror  (lane ^ 15 within 16)
#define DPP_XOR8 0x128   // row_ror:8   (lane ^ 8  within 16)

// 256 threads / 4 waves per batch element.
//   k-group s = tid&15 : h-k range [8s,8s+8), x-k range [4s,4s+4)
//   j-group g = tid>>4 : j range [8g, 8g+8)
// Per step each thread: 2 b128 h-reads + 1 b128 x-read + 48 pk_fma, then a
// DPP butterfly reduce-scatter over the 16-lane k-group (masks 1,2,15,8 —
// all DPP-able; slot m holds j = 8g + (m ^ i(l)) so every stage is
// new[s] = v[2s] + dpp(v[2s+1]) with static indices). Lane ends with
// z[8g + i(l)], i(l) = (l0^l2) | ((l1^l2)<<1) | (l2<<2).
// h stored padded: float addr = k + (k>>3)*4 (16B-aligned, <=2-way banks).
__launch_bounds__(256, 1)
__global__ void rnn_dpp_kernel(const float* __restrict__ x,
                               const float* __restrict__ Wx_w,
                               const float* __restrict__ Wx_b,
                               const float* __restrict__ Wh_w,
                               const float* __restrict__ Wh_b,
                               const float* __restrict__ fc_w,
                               const float* __restrict__ fc_b,
                               float* __restrict__ out) {
  const int b = blockIdx.x;
  const int tid = threadIdx.x;
  const int l = tid & 63;
  const int s = tid & 15;  // k-group
  const int g = tid >> 4;  // j-group (0..15)
  const int l0 = l & 1, l1 = (l >> 1) & 1, l2 = (l >> 2) & 1;
  const int ii = (l0 ^ l2) | ((l1 ^ l2) << 1) | (l2 << 2);
  const int jf = 8 * g + ii;  // the j this lane finalizes

  __shared__ __align__(16) float hA[192], hB[192];       // padded h buffers
  __shared__ __align__(16) float xsm[2][CHUNK * INSZ];   // 2 x 4KB

  // ---- weights: slot m holds row j = 8g + (m ^ ii) ----
  v2f wh2[8][4], wx2[8][2];
#pragma unroll
  for (int m = 0; m < 8; ++m) {
    const int row = 8 * g + (m ^ ii);
    const float* p = Wh_w + row * HID + 8 * s;
    v4f t0 = *(const v4f*)p;
    v4f t1 = *(const v4f*)(p + 4);
    wh2[m][0] = (v2f){t0.x, t0.y};
    wh2[m][1] = (v2f){t0.z, t0.w};
    wh2[m][2] = (v2f){t1.x, t1.y};
    wh2[m][3] = (v2f){t1.z, t1.w};
    const float* q = Wx_w + row * INSZ + 4 * s;
    v4f t2 = *(const v4f*)q;
    wx2[m][0] = (v2f){t2.x, t2.y};
    wx2[m][1] = (v2f){t2.z, t2.w};
  }
  // pin weights to arch VGPRs (discourage AGPR/remat games)
#pragma unroll
  for (int m = 0; m < 8; ++m) {
#pragma unroll
    for (int kk = 0; kk < 4; ++kk) asm volatile("" : "+v"(wh2[m][kk]));
#pragma unroll
    for (int kk = 0; kk < 2; ++kk) asm volatile("" : "+v"(wx2[m][kk]));
  }
  const float bc = Wx_b[jf] + Wh_b[jf];

  const float* xg = x + (size_t)b * TSTEPS * INSZ;

  // ---- init h0 = 0 ----
  if (tid < 192) hA[tid] = 0.f;

  // ---- stage chunk 0 ----
  {
    const AS1 float* gp = (const AS1 float*)(xg + tid * 4);
    AS3 float* d = (AS3 float*)(&xsm[0][(tid >> 6) * 256]);
    __builtin_amdgcn_global_load_lds(gp, d, 16, 0, 0);
  }
  asm volatile("s_waitcnt vmcnt(0) lgkmcnt(0)\ns_barrier" ::: "memory");

  // ---- recurrence ----
  for (int tc = 0; tc < NCHUNK; ++tc) {
    if (tc + 1 < NCHUNK) {
      const AS1 float* gp =
          (const AS1 float*)(xg + (size_t)(tc + 1) * CHUNK * INSZ + tid * 4);
      AS3 float* d = (AS3 float*)(&xsm[(tc + 1) & 1][(tid >> 6) * 256]);
      __builtin_amdgcn_global_load_lds(gp, d, 16, 0, 0);
    }
    const float* xc = xsm[tc & 1];

#pragma unroll
    for (int ts = 0; ts < CHUNK; ++ts) {
      const float* hin = (ts & 1) ? hB : hA;   // step parity static (CHUNK even)
      float* hout = (ts & 1) ? hA : hB;

      v4f xv = *(const v4f*)&xc[ts * INSZ + 4 * s];
      const float* hp = hin + 12 * s;          // padded addr of k=8s
      v4f h0 = *(const v4f*)hp;
      v4f h1 = *(const v4f*)(hp + 4);

      v2f hx0 = (v2f){h0.x, h0.y}, hx1 = (v2f){h0.z, h0.w};
      v2f hx2 = (v2f){h1.x, h1.y}, hx3 = (v2f){h1.z, h1.w};
      v2f xx0 = (v2f){xv.x, xv.y}, xx1 = (v2f){xv.z, xv.w};

      float a0, a1, a2, a3, a4, a5, a6, a7;
      float* aptr[8] = {&a0, &a1, &a2, &a3, &a4, &a5, &a6, &a7};
#pragma unroll
      for (int m = 0; m < 8; ++m) {
        v2f acc = wh2[m][0] * hx0;
        acc = __builtin_elementwise_fma(wh2[m][1], hx1, acc);
        acc = __builtin_elementwise_fma(wh2[m][2], hx2, acc);
        acc = __builtin_elementwise_fma(wh2[m][3], hx3, acc);
        acc = __builtin_elementwise_fma(wx2[m][0], xx0, acc);
        acc = __builtin_elementwise_fma(wx2[m][1], xx1, acc);
        *aptr[m] = acc.x + acc.y;
      }

      // butterfly reduce-scatter over the 16-lane k-group (VALU DPP only)
      float b0 = a0 + dppf<DPP_XOR1>(a1);
      float b1 = a2 + dppf<DPP_XOR1>(a3);
      float b2 = a4 + dppf<DPP_XOR1>(a5);
      float b3 = a6 + dppf<DPP_XOR1>(a7);
      float c0 = b0 + dppf<DPP_XOR2>(b1);
      float c1 = b2 + dppf<DPP_XOR2>(b3);
      float dd = c0 + dppf<DPP_XOR15>(c1);
      float z  = dd + dppf<DPP_XOR8>(dd);

      // tanh(z+bc) = 1 - 2/(exp2(2*(z+bc)*log2e)+1)
      z += bc;
      float e = __builtin_amdgcn_exp2f(z * 2.8853900817779268f);
      float hn = 1.f - 2.f * __builtin_amdgcn_rcpf(e + 1.f);

      if ((l & 8) == 0) hout[12 * g + ii] = hn;  // padded addr of j=jf

      if (ts == CHUNK - 1) {
        asm volatile("s_waitcnt vmcnt(0) lgkmcnt(0)\ns_barrier" ::: "memory");
      } else {
        asm volatile("s_waitcnt lgkmcnt(0)\ns_barrier" ::: "memory");
      }
    }
  }

  // ---- epilogue: logits + softmax over 64, one wave; final h in hA ----
  if (tid < 64) {
    float acc = fc_b[tid];
    const float* fr = fc_w + tid * HID;
#pragma unroll
    for (int k8 = 0; k8 < 16; ++k8) {
      v4f w0 = *(const v4f*)(fr + 8 * k8);
      v4f w1 = *(const v4f*)(fr + 8 * k8 + 4);
      const float* hh = &hA[12 * k8];
      v4f p0 = *(const v4f*)hh;
      v4f p1 = *(const v4f*)(hh + 4);
      acc = fmaf(w0.x, p0.x, acc);
      acc = fmaf(w0.y, p0.y, acc);
      acc = fmaf(w0.z, p0.z, acc);
      acc = fmaf(w0.w, p0.w, acc);
      acc = fmaf(w1.x, p1.x, acc);
      acc = fmaf(w1.y, p1.y, acc);
      acc = fmaf(w1.z, p1.z, acc);
      acc = fmaf(w1.w, p1.w, acc);
    }
    float m = acc;
#pragma unroll
    for (int off = 32; off >= 1; off >>= 1) m = fmaxf(m, __shfl_xor(m, off, 64));
    float e = __builtin_amdgcn_exp2f((acc - m) * 1.4426950408889634f);
    float ssum = e;
#pragma unroll
    for (int off = 32; off >= 1; off >>= 1) ssum += __shfl_xor(ssum, off, 64);
    out[b * OUTSZ + tid] = e / ssum;
  }
}

extern "C" void kernel_launch(void* const* d_in, const int* in_sizes, int n_in,
                              void* d_out, int out_size, void* d_ws, size_t ws_size,
                              hipStream_t stream) {
  const float* x    = (const float*)d_in[0];
  const float* Wx_w = (const float*)d_in[1];
  const float* Wx_b = (const float*)d_in[2];
  const float* Wh_w = (const float*)d_in[3];
  const float* Wh_b = (const float*)d_in[4];
  const float* fc_w = (const float*)d_in[5];
  const float* fc_b = (const float*)d_in[6];
  float* out = (float*)d_out;

  rnn_dpp_kernel<<<BATCH, 256, 0, stream>>>(x, Wx_w, Wx_b, Wh_w, Wh_b, fc_w, fc_b, out);
}

// Round 6
// 538.362 us; speedup vs baseline: 6.6171x; 1.0243x over previous
//
#include <hip/hip_runtime.h>

#define BATCH 256
#define TSTEPS 2048
#define INSZ 64
#define HID 128
#define OUTSZ 64
#define NTHR 512
#define CHUNK 32                 // timesteps of x per staging buffer (8KB)
#define NCHUNK (TSTEPS / CHUNK)  // 64

typedef float v2f __attribute__((ext_vector_type(2)));
typedef float v4f __attribute__((ext_vector_type(4)));

#define AS1 __attribute__((address_space(1)))
#define AS3 __attribute__((address_space(3)))

// DPP cross-lane move (VALU pipe). Patterns stay within a 16-lane row.
template <int CTRL>
__device__ __forceinline__ float dppf(float v) {
  return __int_as_float(__builtin_amdgcn_update_dpp(
      0, __float_as_int(v), CTRL, 0xF, 0xF, true));
}
#define DPP_XOR1 0xB1    // quad_perm:[1,0,3,2]
#define DPP_XOR2 0x4E    // quad_perm:[2,3,0,1]
#define DPP_XOR15 0x140  // row_mirror (lane ^ 15 within 16)
#define DPP_XOR8 0x128   // row_ror:8  (lane ^ 8  within 16)

// guaranteed packed f32 math (2 MACs / instr)
__device__ __forceinline__ v2f pk_mul(v2f a, v2f b) {
  v2f d; asm("v_pk_mul_f32 %0, %1, %2" : "=v"(d) : "v"(a), "v"(b)); return d;
}
__device__ __forceinline__ v2f pk_fma(v2f a, v2f b, v2f c) {
  v2f d; asm("v_pk_fma_f32 %0, %1, %2, %3" : "=v"(d) : "v"(a), "v"(b), "v"(c)); return d;
}

// 512 threads / 8 waves per batch element (2 waves per SIMD -> stall interleave).
//   k-group s = tid&15 : h-k range [8s,8s+8), x-k range [4s,4s+4)
//   j-group g = tid>>4 : j range [4g, 4g+4)   (32 j-groups)
// Slot m in [0,4) holds row j = 4g + (m ^ c),  c = (s0^s2)|((s1^s2)<<1).
// Reduce over the 16-lane k-group: DPP stages xor1 (slots), xor2 (slots),
// xor15, xor8 (lanes). Lanes s<4 end holding j = 4g+s and write h.
// h padded: addr = k + (k>>3)*4 (16B aligned, <=2-way banks). Barriers are raw
// s_barrier + lgkmcnt(0); vmcnt drained once per 32-step chunk (loads 31 steps old).
__launch_bounds__(NTHR, 1)
__global__ void rnn_dpp512_kernel(const float* __restrict__ x,
                                  const float* __restrict__ Wx_w,
                                  const float* __restrict__ Wx_b,
                                  const float* __restrict__ Wh_w,
                                  const float* __restrict__ Wh_b,
                                  const float* __restrict__ fc_w,
                                  const float* __restrict__ fc_b,
                                  float* __restrict__ out) {
  const int b = blockIdx.x;
  const int tid = threadIdx.x;
  const int s = tid & 15;  // k-group (= lane&15)
  const int g = tid >> 4;  // j-group (0..31)
  const int s0 = s & 1, s1 = (s >> 1) & 1, s2 = (s >> 2) & 1;
  const int c = (s0 ^ s2) | ((s1 ^ s2) << 1);
  const int jf = 4 * g + c;                  // the j this lane finalizes
  const int jp = jf + ((jf >> 3) << 2);      // padded write index

  __shared__ __align__(16) float hA[192], hB[192];        // padded h buffers
  __shared__ __align__(16) float xsm[2][CHUNK * INSZ];    // 2 x 8KB

  // ---- weights: slot m holds row j = 4g + (m ^ c) ----
  v2f wh2[4][4], wx2[4][2];
#pragma unroll
  for (int m = 0; m < 4; ++m) {
    const int row = 4 * g + (m ^ c);
    const float* p = Wh_w + row * HID + 8 * s;
    v4f t0 = *(const v4f*)p;
    v4f t1 = *(const v4f*)(p + 4);
    wh2[m][0] = (v2f){t0.x, t0.y};
    wh2[m][1] = (v2f){t0.z, t0.w};
    wh2[m][2] = (v2f){t1.x, t1.y};
    wh2[m][3] = (v2f){t1.z, t1.w};
    const float* q = Wx_w + row * INSZ + 4 * s;
    v4f t2 = *(const v4f*)q;
    wx2[m][0] = (v2f){t2.x, t2.y};
    wx2[m][1] = (v2f){t2.z, t2.w};
  }
  const float bc = Wx_b[jf] + Wh_b[jf];

  const float* xg = x + (size_t)b * TSTEPS * INSZ;

  // ---- init h0 = 0 ----
  if (tid < 192) hA[tid] = 0.f;

  // ---- stage chunk 0: 512 threads x 16B = 8KB ----
  {
    const AS1 float* gp = (const AS1 float*)(xg + tid * 4);
    AS3 float* d = (AS3 float*)(&xsm[0][(tid >> 6) * 256]);
    __builtin_amdgcn_global_load_lds(gp, d, 16, 0, 0);
  }
  asm volatile("s_waitcnt vmcnt(0) lgkmcnt(0)\ns_barrier" ::: "memory");

  // ---- recurrence ----
  for (int tc = 0; tc < NCHUNK; ++tc) {
    // re-pin weights to arch VGPRs once per chunk (blocks AGPR shuttling)
#pragma unroll
    for (int m = 0; m < 4; ++m) {
#pragma unroll
      for (int kk = 0; kk < 4; ++kk) asm("" : "+v"(wh2[m][kk]));
#pragma unroll
      for (int kk = 0; kk < 2; ++kk) asm("" : "+v"(wx2[m][kk]));
    }
    if (tc + 1 < NCHUNK) {
      const AS1 float* gp =
          (const AS1 float*)(xg + (size_t)(tc + 1) * CHUNK * INSZ + tid * 4);
      AS3 float* d = (AS3 float*)(&xsm[(tc + 1) & 1][(tid >> 6) * 256]);
      __builtin_amdgcn_global_load_lds(gp, d, 16, 0, 0);
    }
    const float* xc = xsm[tc & 1];
    v4f xcur = *(const v4f*)&xc[4 * s];  // ts = 0 (buffer just drained)

#pragma unroll
    for (int ts = 0; ts < CHUNK; ++ts) {
      const float* hin = (ts & 1) ? hB : hA;  // parity static (CHUNK even)
      float* hout = (ts & 1) ? hA : hB;

      // h reads at step head (the only exposed LDS latency)
      const float* hp = hin + 12 * s;
      v4f h0 = *(const v4f*)hp;
      v4f h1 = *(const v4f*)(hp + 4);

      // prefetch next step's x (no h dependency; latency hidden a full step)
      v4f xnext;
      if (ts + 1 < CHUNK) xnext = *(const v4f*)&xc[(ts + 1) * INSZ + 4 * s];

      v2f xx0 = (v2f){xcur.x, xcur.y}, xx1 = (v2f){xcur.z, xcur.w};
      v2f hx0 = (v2f){h0.x, h0.y}, hx1 = (v2f){h0.z, h0.w};
      v2f hx2 = (v2f){h1.x, h1.y}, hx3 = (v2f){h1.z, h1.w};

      float a0, a1, a2, a3;
      float* aptr[4] = {&a0, &a1, &a2, &a3};
#pragma unroll
      for (int m = 0; m < 4; ++m) {
        v2f acc = pk_mul(wx2[m][0], xx0);          // x-part first (ready early)
        acc = pk_fma(wx2[m][1], xx1, acc);
        acc = pk_fma(wh2[m][0], hx0, acc);
        acc = pk_fma(wh2[m][1], hx1, acc);
        acc = pk_fma(wh2[m][2], hx2, acc);
        acc = pk_fma(wh2[m][3], hx3, acc);
        *aptr[m] = acc.x + acc.y;
      }

      // DPP butterfly reduce-scatter over the 16-lane k-group
      float b0 = a0 + dppf<DPP_XOR1>(a1);
      float b1 = a2 + dppf<DPP_XOR1>(a3);
      float w  = b0 + dppf<DPP_XOR2>(b1);
      float u  = w + dppf<DPP_XOR15>(w);
      float z  = u + dppf<DPP_XOR8>(u);

      // tanh(z+bc) = 1 - 2/(exp2(2*(z+bc)*log2e)+1)
      z += bc;
      float e = __builtin_amdgcn_exp2f(z * 2.8853900817779268f);
      float hn = fmaf(-2.f, __builtin_amdgcn_rcpf(e + 1.f), 1.f);

      if (s < 4) hout[jp] = hn;  // lanes s=0..3 hold j=4g+s

      if (ts + 1 < CHUNK) xcur = xnext;

      if (ts == CHUNK - 1) {
        // vmcnt drain folded here: next chunk's loads are 31 steps old -> free
        asm volatile("s_waitcnt vmcnt(0) lgkmcnt(0)\ns_barrier" ::: "memory");
      } else {
        asm volatile("s_waitcnt lgkmcnt(0)\ns_barrier" ::: "memory");
      }
    }
  }

  // ---- epilogue: logits + softmax over 64, one wave; final h in hA ----
  if (tid < 64) {
    float acc = fc_b[tid];
    const float* fr = fc_w + tid * HID;
#pragma unroll
    for (int k8 = 0; k8 < 16; ++k8) {
      v4f w0 = *(const v4f*)(fr + 8 * k8);
      v4f w1 = *(const v4f*)(fr + 8 * k8 + 4);
      const float* hh = &hA[12 * k8];
      v4f p0 = *(const v4f*)hh;
      v4f p1 = *(const v4f*)(hh + 4);
      acc = fmaf(w0.x, p0.x, acc);
      acc = fmaf(w0.y, p0.y, acc);
      acc = fmaf(w0.z, p0.z, acc);
      acc = fmaf(w0.w, p0.w, acc);
      acc = fmaf(w1.x, p1.x, acc);
      acc = fmaf(w1.y, p1.y, acc);
      acc = fmaf(w1.z, p1.z, acc);
      acc = fmaf(w1.w, p1.w, acc);
    }
    float m = acc;
#pragma unroll
    for (int off = 32; off >= 1; off >>= 1) m = fmaxf(m, __shfl_xor(m, off, 64));
    float e = __builtin_amdgcn_exp2f((acc - m) * 1.4426950408889634f);
    float ssum = e;
#pragma unroll
    for (int off = 32; off >= 1; off >>= 1) ssum += __shfl_xor(ssum, off, 64);
    out[b * OUTSZ + tid] = e / ssum;
  }
}

extern "C" void kernel_launch(void* const* d_in, const int* in_sizes, int n_in,
                              void* d_out, int out_size, void* d_ws, size_t ws_size,
                              hipStream_t stream) {
  const float* x    = (const float*)d_in[0];
  const float* Wx_w = (const float*)d_in[1];
  const float* Wx_b = (const float*)d_in[2];
  const float* Wh_w = (const float*)d_in[3];
  const float* Wh_b = (const float*)d_in[4];
  const float* fc_w = (const float*)d_in[5];
  const float* fc_b = (const float*)d_in[6];
  float* out = (float*)d_out;

  rnn_dpp512_kernel<<<BATCH, NTHR, 0, stream>>>(x, Wx_w, Wx_b, Wh_w, Wh_b, fc_w, fc_b, out);
}